// Round 9
// baseline (1995.796 us; speedup 1.0000x reference)
//
#include <hip/hip_runtime.h>
#include <cstdint>
#include <cstddef>

// Problem constants
#define B_    4
#define S_    4096
#define H_    2048
#define DFF_  8192
#define KSEL  2048            // k = int(0.5 * S)
#define CAP   2304            // padded per-batch compact capacity (18*128)
#define TPB   18              // 128-row tiles per batch (CAP/128)
#define TCAP  (B_*CAP)        // 9216 compact rows (padded)
#define NRT   (TCAP/128)      // 72 row tiles of 128

typedef unsigned short ushort_t;
typedef __attribute__((ext_vector_type(8))) __bf16 bf16x8;
typedef __attribute__((ext_vector_type(4))) float f32x4;

// f32 -> bf16 round-to-nearest-even
__device__ __forceinline__ ushort_t f2bf(float f) {
  union { float f; uint32_t u; } v; v.f = f;
  uint32_t u = v.u;
  return (ushort_t)((u + 0x7FFFu + ((u >> 16) & 1u)) >> 16);
}
__device__ __forceinline__ float bf2f(ushort_t h) {
  union { uint32_t u; float f; } v; v.u = ((uint32_t)h) << 16;
  return v.f;
}

// async global->LDS, 16B per lane. LDS dest is wave-uniform base + lane*16.
__device__ __forceinline__ void gload16(const void* g, void* l) {
  __builtin_amdgcn_global_load_lds(
      (const __attribute__((address_space(1))) void*)g,
      (__attribute__((address_space(3))) void*)l, 16, 0, 0);
}

// ---------------------------------------------------------------- weights:
// convert f32 W[K][N] -> bf16 Wt[N][K] (transposed so GEMM B-operand stages
// with K contiguous per n-row, same pattern as A).
__global__ __launch_bounds__(256) void wconvT_k(const float* __restrict__ W,
                                                ushort_t* __restrict__ Wt,
                                                int K, int N) {
  __shared__ float tile[64][65];
  int k0 = blockIdx.x * 64, n0 = blockIdx.y * 64;
  int tx = threadIdx.x & 63, ty = threadIdx.x >> 6;
  #pragma unroll
  for (int yy = ty; yy < 64; yy += 4)
    tile[yy][tx] = W[(size_t)(k0 + yy) * N + n0 + tx];
  __syncthreads();
  #pragma unroll
  for (int yy = ty; yy < 64; yy += 4)
    Wt[(size_t)(n0 + yy) * K + k0 + tx] = f2bf(tile[tx][yy]);
}

// ---------------------------------------------------------------- router
__global__ __launch_bounds__(256) void router_k(const float* __restrict__ x,
                                                const float* __restrict__ wr,
                                                const float* __restrict__ br,
                                                float* __restrict__ wts) {
  int t = blockIdx.x * 4 + (threadIdx.x >> 6);
  int lane = threadIdx.x & 63;
  const float4* xr = (const float4*)(x + (size_t)t * H_);
  const float4* w4 = (const float4*)wr;
  float s = 0.f;
  #pragma unroll
  for (int j = 0; j < 8; ++j) {
    float4 a = xr[lane + 64 * j], b = w4[lane + 64 * j];
    s = fmaf(a.x, b.x, s); s = fmaf(a.y, b.y, s);
    s = fmaf(a.z, b.z, s); s = fmaf(a.w, b.w, s);
  }
  #pragma unroll
  for (int o = 32; o > 0; o >>= 1) s += __shfl_xor(s, o, 64);
  if (lane == 0) wts[t] = 1.f / (1.f + expf(-(s + br[0])));
}

// ---------------------------------------------------------------- top-k
__global__ __launch_bounds__(1024) void kth_k(const float* __restrict__ wts,
                                              float* __restrict__ thr) {
  __shared__ float a[S_];
  int b = blockIdx.x, tid = threadIdx.x;
  const float* wb = wts + b * S_;
  for (int i = tid; i < S_; i += 1024) a[i] = wb[i];
  for (int size = 2; size <= S_; size <<= 1) {
    for (int stride = size >> 1; stride > 0; stride >>= 1) {
      __syncthreads();
      for (int t = tid; t < S_ / 2; t += 1024) {
        int i = ((t / stride) * (stride << 1)) + (t % stride);
        int j = i + stride;
        bool up = ((i & size) == 0);
        float ai = a[i], aj = a[j];
        if ((ai > aj) == up) { a[i] = aj; a[j] = ai; }
      }
    }
  }
  __syncthreads();
  if (tid == 0) thr[b] = a[S_ - KSEL];  // ascending sort: k-th largest
}

// ---------------------------------------------------------------- compact
__global__ __launch_bounds__(1024) void compact_k(const float* __restrict__ wts,
                                                  const float* __restrict__ thr,
                                                  int* __restrict__ idx,
                                                  int* __restrict__ counts) {
  __shared__ int sc[1024];
  int b = blockIdx.x, tid = threadIdx.x;
  float th = thr[b];
  int m[4], cnt = 0;
  #pragma unroll
  for (int e = 0; e < 4; ++e) {
    m[e] = (wts[b * S_ + tid * 4 + e] >= th) ? 1 : 0;
    cnt += m[e];
  }
  sc[tid] = cnt;
  __syncthreads();
  for (int off = 1; off < 1024; off <<= 1) {
    int add = (tid >= off) ? sc[tid - off] : 0;
    __syncthreads();
    sc[tid] += add;
    __syncthreads();
  }
  int excl = sc[tid] - cnt;
  int total = sc[1023];
  int cl = total < CAP ? total : CAP;
  #pragma unroll
  for (int e = 0; e < 4; ++e) {
    if (m[e]) {
      if (excl < CAP) idx[b * CAP + excl] = b * S_ + tid * 4 + e;
      excl++;
    }
  }
  for (int j2 = tid; j2 < CAP; j2 += 1024)
    if (j2 >= cl) idx[b * CAP + j2] = -1;
  if (tid == 0) counts[b] = cl;
}

// ---------------------------------------------------------------- rmsnorm
template <int MODE>
__global__ __launch_bounds__(256) void rms_k(const float* __restrict__ src,
                                             const float* __restrict__ w,
                                             const int* __restrict__ idx,
                                             const int* __restrict__ counts,
                                             ushort_t* __restrict__ dst) {
  int r = blockIdx.x * 4 + (threadIdx.x >> 6);
  int lane = threadIdx.x & 63;
  ushort4* drow = (ushort4*)(dst + (size_t)r * H_);
  const float* s;
  if (MODE == 0) {
    int b = r / CAP, local = r % CAP;
    if (local >= counts[b]) {
      ushort4 z; z.x = z.y = z.z = z.w = 0;
      #pragma unroll
      for (int j = 0; j < 8; ++j) drow[lane + 64 * j] = z;
      return;
    }
    s = src + (size_t)idx[r] * H_;
  } else {
    s = src + (size_t)r * H_;
  }
  const float4* s4 = (const float4*)s;
  float4 v[8];
  float ss = 0.f;
  #pragma unroll
  for (int j = 0; j < 8; ++j) {
    v[j] = s4[lane + 64 * j];
    ss = fmaf(v[j].x, v[j].x, ss); ss = fmaf(v[j].y, v[j].y, ss);
    ss = fmaf(v[j].z, v[j].z, ss); ss = fmaf(v[j].w, v[j].w, ss);
  }
  #pragma unroll
  for (int o = 32; o > 0; o >>= 1) ss += __shfl_xor(ss, o, 64);
  float rstd = rsqrtf(ss * (1.f / H_) + 1e-5f);
  const float4* w4 = (const float4*)w;
  #pragma unroll
  for (int j = 0; j < 8; ++j) {
    float4 ww = w4[lane + 64 * j];
    ushort4 o4;
    o4.x = f2bf(v[j].x * rstd * ww.x);
    o4.y = f2bf(v[j].y * rstd * ww.y);
    o4.z = f2bf(v[j].z * rstd * ww.z);
    o4.w = f2bf(v[j].w * rstd * ww.w);
    drow[lane + 64 * j] = o4;
  }
}

// ---------------------------------------------------------------- out = x init
__global__ void copy_k(const float4* __restrict__ in, float4* __restrict__ out,
                       int n) {
  int i = blockIdx.x * blockDim.x + threadIdx.x;
  int stride = gridDim.x * blockDim.x;
  for (; i < n; i += stride) out[i] = in[i];
}

// ---------------------------------------------------------------- GEMM:
// m97-validated structure: 128x128 tile, BK=64, 4 waves (2x2), 32 KiB LDS ->
// ~3 blocks/CU so independent blocks overlap each other's barrier/staging
// drains (m114). global_load_lds w16 staging, (row&7) chunk-XOR swizzle on
// the GLOBAL source side (linear LDS dest), swizzled ds_read_b128 reads.
// R1 validated this exact staging/read path (absmax 0.031, 0 conflicts).
// EPI 0: outh[r*N+c] = bf16(acc)
// EPI 1: outf[r*H+c] = x[idx[r]] + acc          (RES, f32)
// EPI 2: outh[r*N+c] = bf16(silu(outh[r*N+c]) * acc)   (in-place)
// EPI 3: out[idx[r]*H+c] = xres[r*H+c] + acc    (scatter, skip idx<0)
template <int EPI>
__global__ __launch_bounds__(256) void gemm_k(const ushort_t* __restrict__ A,
                                              const ushort_t* __restrict__ Bt,
                                              int K, int N, int nct,  // nct=N/128
                                              const int* __restrict__ counts,
                                              const int* __restrict__ idx,
                                              const float* __restrict__ xres,
                                              float* __restrict__ outf,
                                              ushort_t* __restrict__ outh) {
  // XCD-aware swizzle (all grids here divisible by 8)
  const int nwg = (int)gridDim.x;
  const int bid = (int)blockIdx.x;
  const int cpx = nwg >> 3;
  const int wg = (bid & 7) * cpx + (bid >> 3);
  const int rt = wg / nct;
  const int ct = wg % nct;
  const int bb = rt / TPB;
  const int local0 = (rt % TPB) << 7;
  if (local0 >= counts[bb]) return;  // fully-invalid row tile

  __shared__ __align__(16) char lds[32768];
  char* ldsA = lds;
  char* ldsB = lds + 16384;

  const int tid = (int)threadIdx.x;
  const int lane = tid & 63;
  const int wave = tid >> 6;
  const int wm = wave >> 1, wn = wave & 1;

  // staging: thread covers (row = inst*32 + tid/8, chunk = tid%8), chunk
  // XOR-swizzled by row&7 on the global source.
  const int srow = tid >> 3;
  const int c16l = (tid & 7) ^ (srow & 7);
  const size_t Kb = (size_t)K * 2;
  const char* aSrc = (const char*)A + (size_t)(rt * 128 + srow) * Kb + (size_t)c16l * 16;
  const char* bSrc = (const char*)Bt + (size_t)(ct * 128 + srow) * Kb + (size_t)c16l * 16;
  char* aDst = ldsA + wave * 1024;
  char* bDst = ldsB + wave * 1024;

  const int frow = lane & 15;  // fragment row within 16
  const int fk = lane >> 4;    // k-chunk 0..3
  const int ax = frow & 7;     // read-side swizzle

  f32x4 acc[4][4];
  #pragma unroll
  for (int i = 0; i < 4; ++i)
    #pragma unroll
    for (int j = 0; j < 4; ++j) acc[i][j] = (f32x4){0.f, 0.f, 0.f, 0.f};

  const int nkt = K >> 6;
  for (int kt = 0; kt < nkt; ++kt) {
    __syncthreads();  // previous compute done before overwrite
    #pragma unroll
    for (int inst = 0; inst < 4; ++inst) {
      gload16(aSrc + (size_t)inst * 32 * Kb + (size_t)kt * 128, aDst + inst * 4096);
      gload16(bSrc + (size_t)inst * 32 * Kb + (size_t)kt * 128, bDst + inst * 4096);
    }
    __syncthreads();  // compiler drains vmcnt before barrier
    #pragma unroll
    for (int ks = 0; ks < 2; ++ks) {
      bf16x8 af[4], bfv[4];
      #pragma unroll
      for (int i = 0; i < 4; ++i) {
        int ar = wm * 64 + i * 16 + frow;
        af[i] = *(const bf16x8*)(ldsA + ar * 128 + (((ks * 4 + fk) ^ ax) << 4));
        int br2 = wn * 64 + i * 16 + frow;
        bfv[i] = *(const bf16x8*)(ldsB + br2 * 128 + (((ks * 4 + fk) ^ ax) << 4));
      }
      #pragma unroll
      for (int i = 0; i < 4; ++i)
        #pragma unroll
        for (int j = 0; j < 4; ++j)
          acc[i][j] = __builtin_amdgcn_mfma_f32_16x16x32_bf16(af[i], bfv[j],
                                                              acc[i][j], 0, 0, 0);
    }
  }

  // epilogue: C/D layout col = lane&15, row = (lane>>4)*4 + q
  const int erow0 = rt * 128 + wm * 64;
  const int ecol0 = ct * 128 + wn * 64;
  const int rq = (lane >> 4) << 2;
  const int cc = lane & 15;
  #pragma unroll
  for (int i = 0; i < 4; ++i) {
    #pragma unroll
    for (int q = 0; q < 4; ++q) {
      int r = erow0 + i * 16 + rq + q;
      if (EPI == 0) {
        #pragma unroll
        for (int j = 0; j < 4; ++j)
          outh[(size_t)r * N + ecol0 + j * 16 + cc] = f2bf(acc[i][j][q]);
      } else if (EPI == 1) {
        int t = idx[r];
        #pragma unroll
        for (int j = 0; j < 4; ++j) {
          int c = ecol0 + j * 16 + cc;
          float xv = (t >= 0) ? xres[(size_t)t * H_ + c] : 0.f;
          outf[(size_t)r * H_ + c] = xv + acc[i][j][q];
        }
      } else if (EPI == 2) {
        #pragma unroll
        for (int j = 0; j < 4; ++j) {
          size_t o = (size_t)r * N + ecol0 + j * 16 + cc;
          float g = bf2f(outh[o]);
          outh[o] = f2bf((g / (1.f + expf(-g))) * acc[i][j][q]);
        }
      } else {
        int t = idx[r];
        if (t >= 0) {
          #pragma unroll
          for (int j = 0; j < 4; ++j) {
            int c = ecol0 + j * 16 + cc;
            outf[(size_t)t * H_ + c] = xres[(size_t)r * H_ + c] + acc[i][j][q];
          }
        }
      }
    }
  }
}

// ---------------------------------------------------------------- launch
extern "C" void kernel_launch(void* const* d_in, const int* in_sizes, int n_in,
                              void* d_out, int out_size, void* d_ws, size_t ws_size,
                              hipStream_t stream) {
  const float* x   = (const float*)d_in[0];
  const float* wr  = (const float*)d_in[1];
  const float* br  = (const float*)d_in[2];
  // d_in[3]=Wq, d_in[4]=Wk: dead code (softmax over singleton axis == 1)
  const float* Wv  = (const float*)d_in[5];
  const float* Wo  = (const float*)d_in[6];
  const float* Wg  = (const float*)d_in[7];
  const float* Wu  = (const float*)d_in[8];
  const float* Wd  = (const float*)d_in[9];
  const float* n1w = (const float*)d_in[10];
  const float* n2w = (const float*)d_in[11];
  float* out = (float*)d_out;

  char* p = (char*)d_ws;
  auto alloc = [&](size_t bytes) {
    char* r = p;
    p += (bytes + 255) & ~(size_t)255;
    return r;
  };
  ushort_t* WvT = (ushort_t*)alloc((size_t)H_ * H_ * 2);
  ushort_t* WoT = (ushort_t*)alloc((size_t)H_ * H_ * 2);
  ushort_t* WgT = (ushort_t*)alloc((size_t)DFF_ * H_ * 2);
  ushort_t* WuT = (ushort_t*)alloc((size_t)DFF_ * H_ * 2);
  ushort_t* WdT = (ushort_t*)alloc((size_t)H_ * DFF_ * 2);
  float* wts    = (float*)alloc((size_t)B_ * S_ * 4);
  float* thr    = (float*)alloc(256);
  int* counts   = (int*)alloc(256);
  int* idx      = (int*)alloc((size_t)TCAP * 4);
  ushort_t* Xn1 = (ushort_t*)alloc((size_t)TCAP * H_ * 2);  // also reused as N2
  ushort_t* Vc  = (ushort_t*)alloc((size_t)TCAP * H_ * 2);
  float* RES    = (float*)alloc((size_t)TCAP * H_ * 4);
  ushort_t* Hb  = (ushort_t*)alloc((size_t)TCAP * DFF_ * 2);  // gate, then h (in-place)
  (void)ws_size; (void)in_sizes; (void)n_in; (void)out_size;

  // weight convert+transpose (bf16, [N][K])
  wconvT_k<<<dim3(H_ / 64, H_ / 64), 256, 0, stream>>>(Wv, WvT, H_, H_);
  wconvT_k<<<dim3(H_ / 64, H_ / 64), 256, 0, stream>>>(Wo, WoT, H_, H_);
  wconvT_k<<<dim3(H_ / 64, DFF_ / 64), 256, 0, stream>>>(Wg, WgT, H_, DFF_);
  wconvT_k<<<dim3(H_ / 64, DFF_ / 64), 256, 0, stream>>>(Wu, WuT, H_, DFF_);
  wconvT_k<<<dim3(DFF_ / 64, H_ / 64), 256, 0, stream>>>(Wd, WdT, DFF_, H_);

  // routing
  router_k<<<(B_ * S_) / 4, 256, 0, stream>>>(x, wr, br, wts);
  kth_k<<<B_, 1024, 0, stream>>>(wts, thr);
  compact_k<<<B_, 1024, 0, stream>>>(wts, thr, idx, counts);

  // n1 = rmsnorm(x) gathered to compact rows (bf16)
  rms_k<0><<<TCAP / 4, 256, 0, stream>>>(x, n1w, idx, counts, Xn1);

  // out = x everywhere (masked rows overwritten by final scatter)
  copy_k<<<2048, 256, 0, stream>>>((const float4*)x, (float4*)out,
                                   (B_ * S_ * H_) / 4);

  // v = n1 @ Wv (bf16)
  gemm_k<0><<<NRT * (H_ / 128), 256, 0, stream>>>(
      Xn1, WvT, H_, H_, H_ / 128, counts, idx, nullptr, nullptr, Vc);
  // res = x + v @ Wo (f32)
  gemm_k<1><<<NRT * (H_ / 128), 256, 0, stream>>>(
      Vc, WoT, H_, H_, H_ / 128, counts, idx, x, RES, nullptr);
  // n2 = rmsnorm(res) (bf16, reuses Xn1 buffer)
  rms_k<1><<<TCAP / 4, 256, 0, stream>>>(RES, n2w, idx, counts, Xn1);
  // g = n2 @ Wg (bf16 -> Hb)
  gemm_k<0><<<NRT * (DFF_ / 128), 256, 0, stream>>>(
      Xn1, WgT, H_, DFF_, DFF_ / 128, counts, idx, nullptr, nullptr, Hb);
  // h = silu(g) * (n2 @ Wu)  (in-place on Hb)
  gemm_k<2><<<NRT * (DFF_ / 128), 256, 0, stream>>>(
      Xn1, WuT, H_, DFF_, DFF_ / 128, counts, idx, nullptr, nullptr, Hb);
  // out[idx] = res + h @ Wd (scatter)
  gemm_k<3><<<NRT * (H_ / 128), 256, 0, stream>>>(
      Hb, WdT, DFF_, H_, H_ / 128, counts, idx, RES, out, nullptr);
}

// Round 11
// 1905.604 us; speedup vs baseline: 1.0473x; 1.0473x over previous
//
#include <hip/hip_runtime.h>
#include <cstdint>
#include <cstddef>

// Problem constants
#define B_    4
#define S_    4096
#define H_    2048
#define DFF_  8192
#define KSEL  2048            // k = int(0.5 * S)
#define CAP   2304            // padded per-batch compact capacity (9*256)
#define TPB   9               // 256-row tiles per batch (CAP/256)
#define TCAP  (B_*CAP)        // 9216 compact rows (padded)
#define NRT   (TCAP/256)      // 36 row tiles of 256

typedef unsigned short ushort_t;
typedef __attribute__((ext_vector_type(8))) __bf16 bf16x8;
typedef __attribute__((ext_vector_type(4))) float f32x4;

// f32 -> bf16 round-to-nearest-even
__device__ __forceinline__ ushort_t f2bf(float f) {
  union { float f; uint32_t u; } v; v.f = f;
  uint32_t u = v.u;
  return (ushort_t)((u + 0x7FFFu + ((u >> 16) & 1u)) >> 16);
}
__device__ __forceinline__ float bf2f(ushort_t h) {
  union { uint32_t u; float f; } v; v.u = ((uint32_t)h) << 16;
  return v.f;
}

// async global->LDS, 16B per lane. LDS dest is wave-uniform base + lane*16.
__device__ __forceinline__ void gload16(const void* g, void* l) {
  __builtin_amdgcn_global_load_lds(
      (const __attribute__((address_space(1))) void*)g,
      (__attribute__((address_space(3))) void*)l, 16, 0, 0);
}

// RAW inline-asm barrier: opaque to the compiler's waitcnt-insertion pass,
// so it does NOT auto-drain vmcnt(0) (the builtin barrier gets a
// conservative drain for outstanding global_load_lds -> kills the counted
// pipeline; R6 vs R8 identical perf was this). Staged-data visibility is
// handled by our explicit counted vmcnt + barrier ledger.
#define SBAR() asm volatile("s_barrier" ::: "memory")

#define VMCNT4 asm volatile("s_waitcnt vmcnt(4)" ::: "memory")
#define VMCNT0 asm volatile("s_waitcnt vmcnt(0)" ::: "memory")

// ---------------------------------------------------------------- weights:
// convert f32 W[K][N] -> bf16 Wt[N][K] (transposed so GEMM B-operand stages
// with K contiguous per n-row, same pattern as A).
__global__ __launch_bounds__(256) void wconvT_k(const float* __restrict__ W,
                                                ushort_t* __restrict__ Wt,
                                                int K, int N) {
  __shared__ float tile[64][65];
  int k0 = blockIdx.x * 64, n0 = blockIdx.y * 64;
  int tx = threadIdx.x & 63, ty = threadIdx.x >> 6;
  #pragma unroll
  for (int yy = ty; yy < 64; yy += 4)
    tile[yy][tx] = W[(size_t)(k0 + yy) * N + n0 + tx];
  __syncthreads();
  #pragma unroll
  for (int yy = ty; yy < 64; yy += 4)
    Wt[(size_t)(n0 + yy) * K + k0 + tx] = f2bf(tile[tx][yy]);
}

// ---------------------------------------------------------------- router
__global__ __launch_bounds__(256) void router_k(const float* __restrict__ x,
                                                const float* __restrict__ wr,
                                                const float* __restrict__ br,
                                                float* __restrict__ wts) {
  int t = blockIdx.x * 4 + (threadIdx.x >> 6);
  int lane = threadIdx.x & 63;
  const float4* xr = (const float4*)(x + (size_t)t * H_);
  const float4* w4 = (const float4*)wr;
  float s = 0.f;
  #pragma unroll
  for (int j = 0; j < 8; ++j) {
    float4 a = xr[lane + 64 * j], b = w4[lane + 64 * j];
    s = fmaf(a.x, b.x, s); s = fmaf(a.y, b.y, s);
    s = fmaf(a.z, b.z, s); s = fmaf(a.w, b.w, s);
  }
  #pragma unroll
  for (int o = 32; o > 0; o >>= 1) s += __shfl_xor(s, o, 64);
  if (lane == 0) wts[t] = 1.f / (1.f + expf(-(s + br[0])));
}

// ---------------------------------------------------------------- top-k
__global__ __launch_bounds__(1024) void kth_k(const float* __restrict__ wts,
                                              float* __restrict__ thr) {
  __shared__ float a[S_];
  int b = blockIdx.x, tid = threadIdx.x;
  const float* wb = wts + b * S_;
  for (int i = tid; i < S_; i += 1024) a[i] = wb[i];
  for (int size = 2; size <= S_; size <<= 1) {
    for (int stride = size >> 1; stride > 0; stride >>= 1) {
      __syncthreads();
      for (int t = tid; t < S_ / 2; t += 1024) {
        int i = ((t / stride) * (stride << 1)) + (t % stride);
        int j = i + stride;
        bool up = ((i & size) == 0);
        float ai = a[i], aj = a[j];
        if ((ai > aj) == up) { a[i] = aj; a[j] = ai; }
      }
    }
  }
  __syncthreads();
  if (tid == 0) thr[b] = a[S_ - KSEL];  // ascending sort: k-th largest
}

// ---------------------------------------------------------------- compact
__global__ __launch_bounds__(1024) void compact_k(const float* __restrict__ wts,
                                                  const float* __restrict__ thr,
                                                  int* __restrict__ idx,
                                                  int* __restrict__ counts) {
  __shared__ int sc[1024];
  int b = blockIdx.x, tid = threadIdx.x;
  float th = thr[b];
  int m[4], cnt = 0;
  #pragma unroll
  for (int e = 0; e < 4; ++e) {
    m[e] = (wts[b * S_ + tid * 4 + e] >= th) ? 1 : 0;
    cnt += m[e];
  }
  sc[tid] = cnt;
  __syncthreads();
  for (int off = 1; off < 1024; off <<= 1) {
    int add = (tid >= off) ? sc[tid - off] : 0;
    __syncthreads();
    sc[tid] += add;
    __syncthreads();
  }
  int excl = sc[tid] - cnt;
  int total = sc[1023];
  int cl = total < CAP ? total : CAP;
  #pragma unroll
  for (int e = 0; e < 4; ++e) {
    if (m[e]) {
      if (excl < CAP) idx[b * CAP + excl] = b * S_ + tid * 4 + e;
      excl++;
    }
  }
  for (int j2 = tid; j2 < CAP; j2 += 1024)
    if (j2 >= cl) idx[b * CAP + j2] = -1;
  if (tid == 0) counts[b] = cl;
}

// ---------------------------------------------------------------- rmsnorm
template <int MODE>
__global__ __launch_bounds__(256) void rms_k(const float* __restrict__ src,
                                             const float* __restrict__ w,
                                             const int* __restrict__ idx,
                                             const int* __restrict__ counts,
                                             ushort_t* __restrict__ dst) {
  int r = blockIdx.x * 4 + (threadIdx.x >> 6);
  int lane = threadIdx.x & 63;
  ushort4* drow = (ushort4*)(dst + (size_t)r * H_);
  const float* s;
  if (MODE == 0) {
    int b = r / CAP, local = r % CAP;
    if (local >= counts[b]) {
      ushort4 z; z.x = z.y = z.z = z.w = 0;
      #pragma unroll
      for (int j = 0; j < 8; ++j) drow[lane + 64 * j] = z;
      return;
    }
    s = src + (size_t)idx[r] * H_;
  } else {
    s = src + (size_t)r * H_;
  }
  const float4* s4 = (const float4*)s;
  float4 v[8];
  float ss = 0.f;
  #pragma unroll
  for (int j = 0; j < 8; ++j) {
    v[j] = s4[lane + 64 * j];
    ss = fmaf(v[j].x, v[j].x, ss); ss = fmaf(v[j].y, v[j].y, ss);
    ss = fmaf(v[j].z, v[j].z, ss); ss = fmaf(v[j].w, v[j].w, ss);
  }
  #pragma unroll
  for (int o = 32; o > 0; o >>= 1) ss += __shfl_xor(ss, o, 64);
  float rstd = rsqrtf(ss * (1.f / H_) + 1e-5f);
  const float4* w4 = (const float4*)w;
  #pragma unroll
  for (int j = 0; j < 8; ++j) {
    float4 ww = w4[lane + 64 * j];
    ushort4 o4;
    o4.x = f2bf(v[j].x * rstd * ww.x);
    o4.y = f2bf(v[j].y * rstd * ww.y);
    o4.z = f2bf(v[j].z * rstd * ww.z);
    o4.w = f2bf(v[j].w * rstd * ww.w);
    drow[lane + 64 * j] = o4;
  }
}

// ---------------------------------------------------------------- out = x init
__global__ void copy_k(const float4* __restrict__ in, float4* __restrict__ out,
                       int n) {
  int i = blockIdx.x * blockDim.x + threadIdx.x;
  int stride = gridDim.x * blockDim.x;
  for (; i < n; i += stride) out[i] = in[i];
}

// ---------------------------------------------------------------- GEMM:
// 256x256 tile, BK=64, 8 waves (2x4). 2 K-tiles per loop iteration, 8 phases.
// COUNTED vmcnt pipeline (T4) with RAW asm s_barrier (no compiler auto-drain).
// One half-tile (2 gloads/thread) staged per phase; vmcnt(4) only at phases
// 3 and 7 -> 2 half-tiles always in flight. Buffer lifetimes: restage
// A(kt+1)@p0,p1 / A(kt+2)@p4,p5; B(kt+2)@p2,p3 / B(kt+3)@p6,p7. Per-wave
// vmcnt + shared barrier precede any cross-wave read of staged data.
// (row&7) chunk-XOR swizzle on the GLOBAL source side (linear gload dest),
// matching swizzled ds_read_b128. ds_reads precede stage-issues in program
// order so any conservative compiler wait covers only >=2-phase-old loads.
// EPI 0: outh[r*N+c] = bf16(acc)
// EPI 1: outf[r*H+c] = x[idx[r]] + acc          (RES, f32)
// EPI 2: outh[r*N+c] = bf16(silu(gsrc[r*N+c]) * acc)   (in-place ok)
// EPI 3: out[idx[r]*H+c] = xres[r*H+c] + acc    (scatter, skip idx<0)

#define PHASE(KT, Q, STAGE_STMT, WAIT_STMT)                                    \
  {                                                                            \
    const char* curA_ = lds + (((KT) & 1) << 15);                              \
    const char* curB_ = lds + 65536 + (((KT) & 1) << 15);                      \
    bf16x8 af[2][2];                                                           \
    _Pragma("unroll") for (int i_ = 0; i_ < 2; ++i_) {                         \
      const int row_ = wm * 128 + (2 * (Q) + i_) * 16 + frow;                  \
      _Pragma("unroll") for (int ks_ = 0; ks_ < 2; ++ks_)                      \
        af[i_][ks_] = *(const bf16x8*)(curA_ + row_ * 128 +                    \
                                       (((ks_ * 4 + fk) ^ (row_ & 7)) << 4));  \
    }                                                                          \
    if ((Q) == 0) {                                                            \
      _Pragma("unroll") for (int n_ = 0; n_ < 4; ++n_) {                       \
        const int row_ = wn * 64 + n_ * 16 + frow;                             \
        _Pragma("unroll") for (int ks_ = 0; ks_ < 2; ++ks_)                    \
          bfr[n_][ks_] = *(const bf16x8*)(curB_ + row_ * 128 +                 \
                                          (((ks_ * 4 + fk) ^ (row_ & 7)) << 4)); \
      }                                                                        \
    }                                                                          \
    STAGE_STMT;                                                                \
    SBAR();                                                                    \
    __builtin_amdgcn_s_setprio(1);                                             \
    _Pragma("unroll") for (int i_ = 0; i_ < 2; ++i_)                           \
      _Pragma("unroll") for (int ks_ = 0; ks_ < 2; ++ks_)                      \
        _Pragma("unroll") for (int n_ = 0; n_ < 4; ++n_)                       \
          acc[2 * (Q) + i_][n_] = __builtin_amdgcn_mfma_f32_16x16x32_bf16(     \
              af[i_][ks_], bfr[n_][ks_], acc[2 * (Q) + i_][n_], 0, 0, 0);      \
    __builtin_amdgcn_s_setprio(0);                                             \
    WAIT_STMT;                                                                 \
    SBAR();                                                                    \
  }

template <int EPI>
__global__ __launch_bounds__(512, 2) void gemm8_k(
    const ushort_t* __restrict__ A,   // [M][K] bf16
    const ushort_t* __restrict__ Bt,  // [N][K] bf16 (pre-transposed)
    int K, int N, int nct,            // nct = N/256
    const int* __restrict__ counts,
    const int* __restrict__ idx,
    const float* __restrict__ xres,
    const ushort_t* __restrict__ gsrc,
    float* __restrict__ outf,
    ushort_t* __restrict__ outh) {
  // XCD-aware swizzle (grid always divisible by 8 here)
  const int nwg = (int)gridDim.x;
  const int bid = (int)blockIdx.x;
  const int cpx = nwg >> 3;
  const int wg = (bid & 7) * cpx + (bid >> 3);
  const int rt = wg / nct;
  const int ct = wg % nct;
  const int bb = rt / TPB;
  const int local0 = (rt % TPB) << 8;
  if (local0 >= counts[bb]) return;  // fully-invalid row tile

  extern __shared__ __align__(16) char lds[];  // 131072 bytes
  // layout: A-buf0 @0, A-buf1 @32768, B-buf0 @65536, B-buf1 @98304

  const int tid = (int)threadIdx.x;
  const int lane = tid & 63;
  const int wave = tid >> 6;        // 0..7
  const int wm = wave >> 2;         // 0..1 -> rows [wm*128, +128)
  const int wn = wave & 3;          // 0..3 -> cols [wn*64, +64)

  // staging: thread covers (row = i*64 + tid/8, chunk = tid%8) of the
  // [256][64]-bf16 K-tile; chunk XOR-swizzled by row&7 on the global source.
  const int srow = tid >> 3;        // 0..63
  const int schunk = (tid & 7) ^ (srow & 7);
  const size_t Kb = (size_t)K * 2;
  const char* aS = (const char*)A + (size_t)(rt * 256 + srow) * Kb + (size_t)schunk * 16;
  const char* bS = (const char*)Bt + (size_t)(ct * 256 + srow) * Kb + (size_t)schunk * 16;

  const int frow = lane & 15;       // fragment row within 16
  const int fk = lane >> 4;         // k-subchunk 0..3

  // one half-tile = 128 rows x 128B = 2 gload instructions per thread
  auto stageA = [&](int ktile, int h) {
    char* dst = lds + ((ktile & 1) << 15);
    const size_t kcol = (size_t)ktile * 128;
    #pragma unroll
    for (int i = 2 * h; i < 2 * h + 2; ++i)
      gload16(aS + (size_t)i * 64 * Kb + kcol, dst + i * 8192 + wave * 1024);
  };
  auto stageB = [&](int ktile, int h) {
    char* dst = lds + 65536 + ((ktile & 1) << 15);
    const size_t kcol = (size_t)ktile * 128;
    #pragma unroll
    for (int i = 2 * h; i < 2 * h + 2; ++i)
      gload16(bS + (size_t)i * 64 * Kb + kcol, dst + i * 8192 + wave * 1024);
  };

  f32x4 acc[8][4];
  #pragma unroll
  for (int m = 0; m < 8; ++m)
    #pragma unroll
    for (int n = 0; n < 4; ++n) acc[m][n] = (f32x4){0.f, 0.f, 0.f, 0.f};

  // prologue: K-tile 0 fully staged + B(1) issued; vmcnt(4) leaves B(1)'s 4
  // loads in flight (steady-state invariant), barrier makes it collective.
  stageA(0, 0); stageA(0, 1); stageB(0, 0); stageB(0, 1);
  stageB(1, 0); stageB(1, 1);
  VMCNT4;
  SBAR();

  const int nkt = K >> 6;  // always even here (K = 2048 or 8192)
  for (int kt = 0; kt < nkt; kt += 2) {
    const bool pre = (kt + 2 < nkt);
    bf16x8 bfr[4][2];
    // phases 0-3: consume kt; phases 4-7: consume kt+1
    PHASE(kt, 0, stageA(kt + 1, 0), );
    PHASE(kt, 1, stageA(kt + 1, 1), );
    PHASE(kt, 2, if (pre) stageB(kt + 2, 0), );
    PHASE(kt, 3, if (pre) stageB(kt + 2, 1),
          if (pre) { VMCNT4; } else { VMCNT0; });
    PHASE(kt + 1, 0, if (pre) stageA(kt + 2, 0), );
    PHASE(kt + 1, 1, if (pre) stageA(kt + 2, 1), );
    PHASE(kt + 1, 2, if (pre) stageB(kt + 3, 0), );
    PHASE(kt + 1, 3, if (pre) stageB(kt + 3, 1),
          if (pre) { VMCNT4; } else { VMCNT0; });
  }

  // epilogue: C/D layout col = lane&15, row = (lane>>4)*4 + qq
  const int erow0 = rt * 256 + wm * 128;
  const int ecol0 = ct * 256 + wn * 64;
  const int rq = (lane >> 4) << 2;
  const int cc = lane & 15;
  #pragma unroll
  for (int m = 0; m < 8; ++m) {
    #pragma unroll
    for (int qq = 0; qq < 4; ++qq) {
      const int r = erow0 + m * 16 + rq + qq;
      if (EPI == 0) {
        #pragma unroll
        for (int n = 0; n < 4; ++n)
          outh[(size_t)r * N + ecol0 + n * 16 + cc] = f2bf(acc[m][n][qq]);
      } else if (EPI == 1) {
        const int t = idx[r];
        #pragma unroll
        for (int n = 0; n < 4; ++n) {
          const int c = ecol0 + n * 16 + cc;
          const float xv = (t >= 0) ? xres[(size_t)t * H_ + c] : 0.f;
          outf[(size_t)r * H_ + c] = xv + acc[m][n][qq];
        }
      } else if (EPI == 2) {
        #pragma unroll
        for (int n = 0; n < 4; ++n) {
          const size_t o = (size_t)r * N + ecol0 + n * 16 + cc;
          const float g = bf2f(gsrc[o]);
          const float h = (g / (1.f + expf(-g))) * acc[m][n][qq];
          outh[o] = f2bf(h);
        }
      } else {
        const int t = idx[r];
        if (t >= 0) {
          #pragma unroll
          for (int n = 0; n < 4; ++n) {
            const int c = ecol0 + n * 16 + cc;
            outf[(size_t)t * H_ + c] = xres[(size_t)r * H_ + c] + acc[m][n][qq];
          }
        }
      }
    }
  }
}

// ---------------------------------------------------------------- launch
extern "C" void kernel_launch(void* const* d_in, const int* in_sizes, int n_in,
                              void* d_out, int out_size, void* d_ws, size_t ws_size,
                              hipStream_t stream) {
  const float* x   = (const float*)d_in[0];
  const float* wr  = (const float*)d_in[1];
  const float* br  = (const float*)d_in[2];
  // d_in[3]=Wq, d_in[4]=Wk: dead code (softmax over singleton axis == 1)
  const float* Wv  = (const float*)d_in[5];
  const float* Wo  = (const float*)d_in[6];
  const float* Wg  = (const float*)d_in[7];
  const float* Wu  = (const float*)d_in[8];
  const float* Wd  = (const float*)d_in[9];
  const float* n1w = (const float*)d_in[10];
  const float* n2w = (const float*)d_in[11];
  float* out = (float*)d_out;

  char* p = (char*)d_ws;
  auto alloc = [&](size_t bytes) {
    char* r = p;
    p += (bytes + 255) & ~(size_t)255;
    return r;
  };
  ushort_t* WvT = (ushort_t*)alloc((size_t)H_ * H_ * 2);
  ushort_t* WoT = (ushort_t*)alloc((size_t)H_ * H_ * 2);
  ushort_t* WgT = (ushort_t*)alloc((size_t)DFF_ * H_ * 2);
  ushort_t* WuT = (ushort_t*)alloc((size_t)DFF_ * H_ * 2);
  ushort_t* WdT = (ushort_t*)alloc((size_t)H_ * DFF_ * 2);
  float* wts    = (float*)alloc((size_t)B_ * S_ * 4);
  float* thr    = (float*)alloc(256);
  int* counts   = (int*)alloc(256);
  int* idx      = (int*)alloc((size_t)TCAP * 4);
  ushort_t* Xn1 = (ushort_t*)alloc((size_t)TCAP * H_ * 2);  // also reused as N2
  ushort_t* Vc  = (ushort_t*)alloc((size_t)TCAP * H_ * 2);
  float* RES    = (float*)alloc((size_t)TCAP * H_ * 4);
  ushort_t* Hb  = (ushort_t*)alloc((size_t)TCAP * DFF_ * 2);  // gate, then h (in-place)
  (void)ws_size; (void)in_sizes; (void)n_in; (void)out_size;

  // weight convert+transpose (bf16, [N][K])
  wconvT_k<<<dim3(H_ / 64, H_ / 64), 256, 0, stream>>>(Wv, WvT, H_, H_);
  wconvT_k<<<dim3(H_ / 64, H_ / 64), 256, 0, stream>>>(Wo, WoT, H_, H_);
  wconvT_k<<<dim3(H_ / 64, DFF_ / 64), 256, 0, stream>>>(Wg, WgT, H_, DFF_);
  wconvT_k<<<dim3(H_ / 64, DFF_ / 64), 256, 0, stream>>>(Wu, WuT, H_, DFF_);
  wconvT_k<<<dim3(DFF_ / 64, H_ / 64), 256, 0, stream>>>(Wd, WdT, DFF_, H_);

  // routing
  router_k<<<(B_ * S_) / 4, 256, 0, stream>>>(x, wr, br, wts);
  kth_k<<<B_, 1024, 0, stream>>>(wts, thr);
  compact_k<<<B_, 1024, 0, stream>>>(wts, thr, idx, counts);

  // n1 = rmsnorm(x) gathered to compact rows (bf16)
  rms_k<0><<<TCAP / 4, 256, 0, stream>>>(x, n1w, idx, counts, Xn1);

  // out = x everywhere (masked rows overwritten by final scatter)
  copy_k<<<2048, 256, 0, stream>>>((const float4*)x, (float4*)out,
                                   (B_ * S_ * H_) / 4);

  const size_t LDSB = 131072;
  // v = n1 @ Wv (bf16)
  gemm8_k<0><<<NRT * (H_ / 256), 512, LDSB, stream>>>(
      Xn1, WvT, H_, H_, H_ / 256, counts, idx, nullptr, nullptr, nullptr, Vc);
  // res = x + v @ Wo (f32)
  gemm8_k<1><<<NRT * (H_ / 256), 512, LDSB, stream>>>(
      Vc, WoT, H_, H_, H_ / 256, counts, idx, x, nullptr, RES, nullptr);
  // n2 = rmsnorm(res) (bf16, reuses Xn1 buffer)
  rms_k<1><<<TCAP / 4, 256, 0, stream>>>(RES, n2w, idx, counts, Xn1);
  // g = n2 @ Wg (bf16 -> Hb)
  gemm8_k<0><<<NRT * (DFF_ / 256), 512, LDSB, stream>>>(
      Xn1, WgT, H_, DFF_, DFF_ / 256, counts, idx, nullptr, nullptr, nullptr, Hb);
  // h = silu(g) * (n2 @ Wu)  (in-place on Hb)
  gemm8_k<2><<<NRT * (DFF_ / 256), 512, LDSB, stream>>>(
      Xn1, WuT, H_, DFF_, DFF_ / 256, counts, idx, nullptr, Hb, nullptr, Hb);
  // out[idx] = res + h @ Wd (scatter)
  gemm8_k<3><<<NRT * (H_ / 256), 512, LDSB, stream>>>(
      Hb, WdT, DFF_, H_, H_ / 256, counts, idx, RES, nullptr, out, nullptr);
}